// Round 3
// baseline (675.658 us; speedup 1.0000x reference)
//
#include <hip/hip_runtime.h>
#include <hip/hip_cooperative_groups.h>

namespace cg = cooperative_groups;

// Capsule routing, fully fused cooperative kernel. All fp32.
// B=256, K_IN=8, C=1152, J=10, D=16, 4 routing iters.
// m = k*1152 + c (M=9216), n = j*16 + d (N=160).
// Per iter: s[b,n] += sum_m x[b,m]*c_ij[c(m),j(n)]*Wr[m,n]  (atomic, 16-way split-K)
//           v = squash(s) (inline in gemm2 / final stage)
//           b_ij[c,j] += sum_{k,d} Wr[m,n] * (sum_b x[b,m]*v[b,n])
// Grid = 256 blocks x 256 threads (1 block/CU), 8 grid syncs total.

#define C_IN  1152
#define J_U   10
#define M_DIM 9216
#define N_DIM 160
#define B_SZ  256

// ---- ws layout (floats); total 1,608,960 floats = 6.44 MB ----
#define OFF_WR   0                        // fp32 [9216][160]
#define OFF_S    1474560                  // 3 round-robin buffers x [256][160]
#define OFF_BIJ  (1474560 + 3 * 40960)    // fp32 [1152][10]

union SMem {
    struct {                 // gemm1: 18432 floats = 73.7 KB
        float csm[5760];     // softmax(c_ij) for this chunk's 576 rows x 10 j
        float Ws[11520];     // 72 x 160 scaled W panel (reused as reduce buf)
        float Xs[1152];      // 72 m x 16 b transposed x panel
    } g1;
    struct {                 // gemm2: 21040 floats = 84.2 KB
        float Xs[144 * 65];  // 144 m x 64 b (+1 pad) transposed x tile
        float Vs[10240];     // 64 b x 160 n squashed v
        float agg[1440];     // 144 c x 10 j partial agreement
    } g2;
    float sq[256];           // squash-final scratch
};

__global__ __launch_bounds__(256, 1) void caps_fused(const float* __restrict__ x,
                                                     const float* __restrict__ W,
                                                     float* __restrict__ out,
                                                     float* __restrict__ ws) {
    cg::grid_group grid = cg::this_grid();
    __shared__ alignas(16) SMem sm;
    float* Wr   = ws + OFF_WR;
    float* sbuf = ws + OFF_S;
    float* b_ij = ws + OFF_BIJ;
    const int t   = threadIdx.x;
    const int bid = blockIdx.x;
    const int g   = bid * 256 + t;

    // ================= build: zero s0/s1/s2/b_ij (contiguous), build Wr =================
    for (int i = g; i < 3 * 40960 + C_IN * J_U; i += 65536) sbuf[i] = 0.f;
    for (int i = g; i < C_IN * N_DIM; i += 65536) {
        const int c = i / N_DIM, n = i % N_DIM;
        // W[c][j][d][k] flat: c*1280 + n*8 + k ; read full 8-k run (32B) coalesced
        const float4 wlo = *reinterpret_cast<const float4*>(W + (size_t)c * 1280 + n * 8);
        const float4 whi = *reinterpret_cast<const float4*>(W + (size_t)c * 1280 + n * 8 + 4);
        Wr[(size_t)(0 * C_IN + c) * N_DIM + n] = wlo.x;
        Wr[(size_t)(1 * C_IN + c) * N_DIM + n] = wlo.y;
        Wr[(size_t)(2 * C_IN + c) * N_DIM + n] = wlo.z;
        Wr[(size_t)(3 * C_IN + c) * N_DIM + n] = wlo.w;
        Wr[(size_t)(4 * C_IN + c) * N_DIM + n] = whi.x;
        Wr[(size_t)(5 * C_IN + c) * N_DIM + n] = whi.y;
        Wr[(size_t)(6 * C_IN + c) * N_DIM + n] = whi.z;
        Wr[(size_t)(7 * C_IN + c) * N_DIM + n] = whi.w;
    }
    grid.sync();

    for (int it = 0; it < 4; ++it) {
        float* s_cur = sbuf + (it % 3) * 40960;

        // ================= gemm1: 16 m-chunks(576) x 16 b-groups(16) =================
        {
            const int ch = bid >> 4, bg = bid & 15, b0 = bg * 16;
            const int chm0 = ch * 576;
            // inline softmax for this chunk's 576 c-rows
            for (int r = t; r < 576; r += 256) {
                const int c = (chm0 + r) % C_IN;
                float vv[J_U];
                float mx = -1e30f;
#pragma unroll
                for (int j = 0; j < J_U; ++j) { vv[j] = b_ij[c * J_U + j]; mx = fmaxf(mx, vv[j]); }
                float sum = 0.f;
#pragma unroll
                for (int j = 0; j < J_U; ++j) { vv[j] = __expf(vv[j] - mx); sum += vv[j]; }
                const float inv = 1.f / sum;
#pragma unroll
                for (int j = 0; j < J_U; ++j) sm.g1.csm[r * J_U + j] = vv[j] * inv;
            }
            __syncthreads();
            const int ml = t >> 6;          // wave index: m-split within panel
            const int bp = (t >> 4) & 3;    // 4 lanes x 4 b = 16 b
            const int ng = t & 15;          // n0 = ng*10
            float acc[4][10] = {};
            for (int p = 0; p < 8; ++p) {   // 8 panels of 72 m
                const int m0 = chm0 + p * 72;
                float4* Ws4 = reinterpret_cast<float4*>(sm.g1.Ws);
                const float4* Wr4 = reinterpret_cast<const float4*>(Wr);
                for (int i = t; i < 2880; i += 256) {     // 72 x 40 float4
                    const int row = i / 40, q = i - row * 40;
                    const float sc = sm.g1.csm[(p * 72 + row) * J_U + (q >> 2)];
                    const float4 w = Wr4[(size_t)(m0 + row) * 40 + q];
                    Ws4[i] = make_float4(w.x * sc, w.y * sc, w.z * sc, w.w * sc);
                }
                for (int i = t; i < 288; i += 256) {      // 16 b x 18 float4, transpose
                    const int row = i & 15, q = i >> 4;
                    const float4 v = *reinterpret_cast<const float4*>(
                        x + (size_t)(b0 + row) * M_DIM + m0 + 4 * q);
                    sm.g1.Xs[(4 * q + 0) * 16 + row] = v.x;
                    sm.g1.Xs[(4 * q + 1) * 16 + row] = v.y;
                    sm.g1.Xs[(4 * q + 2) * 16 + row] = v.z;
                    sm.g1.Xs[(4 * q + 3) * 16 + row] = v.w;
                }
                __syncthreads();
                const float4* Xs4 = reinterpret_cast<const float4*>(sm.g1.Xs);
                const float2* Ws2 = reinterpret_cast<const float2*>(sm.g1.Ws);
#pragma unroll 2
                for (int mm = 0; mm < 18; ++mm) {
                    const int m = ml * 18 + mm;
                    const float4 xv = Xs4[m * 4 + bp];
#pragma unroll
                    for (int jj = 0; jj < 5; ++jj) {
                        const float2 wv = Ws2[m * 80 + ng * 5 + jj];
                        acc[0][2 * jj]     += xv.x * wv.x;
                        acc[0][2 * jj + 1] += xv.x * wv.y;
                        acc[1][2 * jj]     += xv.y * wv.x;
                        acc[1][2 * jj + 1] += xv.y * wv.y;
                        acc[2][2 * jj]     += xv.z * wv.x;
                        acc[2][2 * jj + 1] += xv.z * wv.y;
                        acc[3][2 * jj]     += xv.w * wv.x;
                        acc[3][2 * jj + 1] += xv.w * wv.y;
                    }
                }
                __syncthreads();
            }
            // reduce acc over the 4 ml-waves (LDS, reusing Ws), then atomics into s
            float* accf = &acc[0][0];
            float* red = sm.g1.Ws;
            if (ml >= 2) {
                float* r = red + ((ml - 2) * 64 + bp * 16 + ng) * 40;
#pragma unroll
                for (int q = 0; q < 40; ++q) r[q] = accf[q];
            }
            __syncthreads();
            if (ml < 2) {
                const float* r = red + (ml * 64 + bp * 16 + ng) * 40;
#pragma unroll
                for (int q = 0; q < 40; ++q) accf[q] += r[q];
            }
            __syncthreads();
            if (ml == 1) {
                float* r = red + (bp * 16 + ng) * 40;
#pragma unroll
                for (int q = 0; q < 40; ++q) r[q] = accf[q];
            }
            __syncthreads();
            if (ml == 0) {
                const float* r = red + (bp * 16 + ng) * 40;
#pragma unroll
                for (int q = 0; q < 40; ++q) accf[q] += r[q];
#pragma unroll
                for (int bi = 0; bi < 4; ++bi)
#pragma unroll
                    for (int jj = 0; jj < 10; ++jj)
                        atomicAdd(&s_cur[(size_t)(b0 + bp * 4 + bi) * N_DIM + ng * 10 + jj],
                                  acc[bi][jj]);
            }
        }
        grid.sync();

        if (it < 3) {
            // ============ gemm2 (+inline squash v, + zero s for iter it+2) ============
            const int mt = bid >> 2, bq = bid & 3;
            const int m0 = mt * 144, bqb = bq * 64;
            float* s_next = sbuf + ((it + 2) % 3) * 40960;
            if (t < 160) s_next[bid * 160 + t] = 0.f;
            for (int i = t; i < 1440; i += 256) sm.g2.agg[i] = 0.f;
            for (int i = t; i < 10240; i += 256)
                sm.g2.Vs[i] = s_cur[(size_t)(bqb + i / N_DIM) * N_DIM + (i % N_DIM)] + 1e-5f;
            for (int i = t; i < 2304; i += 256) {   // 64 b x 36 float4, transpose x
                const int row = i & 63, q = i >> 6;
                const float4 xv = *reinterpret_cast<const float4*>(
                    x + (size_t)(bqb + row) * M_DIM + m0 + 4 * q);
                sm.g2.Xs[(4 * q + 0) * 65 + row] = xv.x;
                sm.g2.Xs[(4 * q + 1) * 65 + row] = xv.y;
                sm.g2.Xs[(4 * q + 2) * 65 + row] = xv.z;
                sm.g2.Xs[(4 * q + 3) * 65 + row] = xv.w;
            }
            __syncthreads();
            for (int i = t; i < 640; i += 256) {    // squash scale per (b, j)
                const int bb = i / J_U, j = i % J_U;
                float mag = 0.f;
#pragma unroll
                for (int d = 0; d < 16; ++d) {
                    const float sv = sm.g2.Vs[bb * N_DIM + j * 16 + d];
                    mag += sv * sv;
                }
                const float fac = sqrtf(mag) / (1.f + mag);
#pragma unroll
                for (int d = 0; d < 16; ++d) sm.g2.Vs[bb * N_DIM + j * 16 + d] *= fac;
            }
            __syncthreads();
            const int tm = t & 15, ng = t >> 4;
            float acc[9][10] = {};
            const float2* Vs2 = reinterpret_cast<const float2*>(sm.g2.Vs);
            for (int b = 0; b < 64; ++b) {
                float xv[9];
#pragma unroll
                for (int i = 0; i < 9; ++i) xv[i] = sm.g2.Xs[(tm * 9 + i) * 65 + b];
#pragma unroll
                for (int jj = 0; jj < 5; ++jj) {
                    const float2 vv = Vs2[b * 80 + ng * 5 + jj];
#pragma unroll
                    for (int i = 0; i < 9; ++i) {
                        acc[i][2 * jj]     += xv[i] * vv.x;
                        acc[i][2 * jj + 1] += xv[i] * vv.y;
                    }
                }
            }
            // fold with Wr into per-block agreement, then flush to b_ij
#pragma unroll
            for (int i = 0; i < 9; ++i) {
                const int rrow = tm * 9 + i;
                const float* wrow = Wr + (size_t)(m0 + rrow) * N_DIM;
                float psum = 0.f;
                int curj = (ng * 10) >> 4;
#pragma unroll
                for (int jj = 0; jj < 10; ++jj) {
                    const int n = ng * 10 + jj;
                    const int j = n >> 4;
                    if (j != curj) {
                        atomicAdd(&sm.g2.agg[rrow * J_U + curj], psum);
                        psum = 0.f;
                        curj = j;
                    }
                    psum += acc[i][jj] * wrow[n];
                }
                atomicAdd(&sm.g2.agg[rrow * J_U + curj], psum);
            }
            __syncthreads();
            const int c0 = m0 % C_IN;   // 144 | 1152: tile never crosses a k-slice
            for (int i = t; i < 1440; i += 256)
                atomicAdd(&b_ij[(size_t)(c0 + i / J_U) * J_U + (i % J_U)], sm.g2.agg[i]);
            grid.sync();
        } else {
            // ================= squash-final -> d_out =================
            float s = 0.f;
            if (t < N_DIM) {
                s = s_cur[(size_t)bid * N_DIM + t] + 1e-5f;
                sm.sq[t] = s * s;
            }
            __syncthreads();
            if (t < N_DIM) {
                const int j0 = t & ~15;
                float mag = 0.f;
#pragma unroll
                for (int d = 0; d < 16; ++d) mag += sm.sq[j0 + d];
                out[(size_t)bid * N_DIM + t] = s * (sqrtf(mag) / (1.f + mag));
            }
        }
    }
}

extern "C" void kernel_launch(void* const* d_in, const int* in_sizes, int n_in,
                              void* d_out, int out_size, void* d_ws, size_t ws_size,
                              hipStream_t stream) {
    const float* x = (const float*)d_in[0];   // (256, 8, 1152) fp32
    const float* W = (const float*)d_in[1];   // (1, 1152, 10, 16, 8) fp32
    float* out = (float*)d_out;               // (256, 10, 16, 1) fp32
    float* ws  = (float*)d_ws;                // needs 6.44 MB
    void* args[] = {(void*)&x, (void*)&W, (void*)&out, (void*)&ws};
    hipLaunchCooperativeKernel((void*)caps_fused, dim3(256), dim3(256), args, 0, stream);
}

// Round 4
// 320.665 us; speedup vs baseline: 2.1071x; 2.1071x over previous
//
#include <hip/hip_runtime.h>

// Capsule routing, factorized, all fp32, multi-kernel (no global atomics).
// B=256, K_IN=8, C=1152, J=10, D=16, 4 iters.
// m = k*1152 + c (M=9216), n = j*16 + d (N=160).
// Per iter: [gemm1] s_part[ch][b][n] = sum_{m in ch} Xt[m,b]*csm[c,j]*Wr[m,n]
//           (gemm1 prologue: b_ij += sum_bq agg_part; csm = softmax(b_ij))
//           [squash] v[b][n] = squash(sum_ch s_part)
//           [gemm2]  agg_part[bq][c][j] = sum_{b in bq,k,d} Wr[m,n]*x[b,m]*v[b,n]

#define C_IN  1152
#define J_U   10
#define M_DIM 9216
#define N_DIM 160
#define B_SZ  256

// ---- ws layout (float offsets); total 9,509,632 floats = 38.0 MB ----
#define OFF_XT   0                    // [9216][256] + 256 pad row
#define OFF_WR   2359552              // [9216][160]
#define OFF_SP   3834112              // [128][256][160]
#define OFF_V    9076992              // [256][160]
#define OFF_B0   9117952              // [1152][10]
#define OFF_B1   9129472              // [1152][10]
#define OFF_AG   9140992              // [4][1152][10]

// ================= prep: transpose x -> Xt, build Wr, zero b_ij/agg =================
__global__ __launch_bounds__(256) void k_prep(const float* __restrict__ x,
                                              const float* __restrict__ W,
                                              float* __restrict__ ws) {
    const int bid = blockIdx.x, t = threadIdx.x;
    if (bid < 576) {                       // 144 m-tiles x 4 b-tiles, 64x64 transpose
        __shared__ float T[64][65];
        const int m0 = (bid % 144) * 64, b0 = (bid / 144) * 64;
        {
            const int b_l = t >> 2, q = t & 3;
            const float* xp = x + (size_t)(b0 + b_l) * M_DIM + m0 + q * 16;
#pragma unroll
            for (int u = 0; u < 4; ++u) {
                const float4 v = *reinterpret_cast<const float4*>(xp + 4 * u);
                T[q * 16 + 4 * u + 0][b_l] = v.x;
                T[q * 16 + 4 * u + 1][b_l] = v.y;
                T[q * 16 + 4 * u + 2][b_l] = v.z;
                T[q * 16 + 4 * u + 3][b_l] = v.w;
            }
        }
        __syncthreads();
        {
            const int m_l = t >> 2, q = t & 3;
            float* Xt = ws + OFF_XT;
            float4* op = reinterpret_cast<float4*>(Xt + (size_t)(m0 + m_l) * B_SZ + b0 + q * 16);
#pragma unroll
            for (int u = 0; u < 4; ++u)
                op[u] = make_float4(T[m_l][q * 16 + 4 * u], T[m_l][q * 16 + 4 * u + 1],
                                    T[m_l][q * 16 + 4 * u + 2], T[m_l][q * 16 + 4 * u + 3]);
        }
    } else if (bid < 2016) {               // Wr[(k*C+c)][n] = W[c][n][k]
        const int i = (bid - 576) * 256 + t;    // [0, 368640)
        const int n = i % N_DIM;
        const int c = (i / N_DIM) % C_IN;
        const int kh = i / (N_DIM * C_IN);      // 0..1
        const float4 w = *reinterpret_cast<const float4*>(W + (size_t)c * 1280 + n * 8 + kh * 4);
        float* Wr = ws + OFF_WR;
        const float wv[4] = {w.x, w.y, w.z, w.w};
#pragma unroll
        for (int j = 0; j < 4; ++j)
            Wr[(size_t)((kh * 4 + j) * C_IN + c) * N_DIM + n] = wv[j];
    } else {                               // zero b_ij (both buffers) + agg_part
        const int idx = (bid - 2016) * 256 + t;   // [0, 11520)
        ws[OFF_B0 + idx] = 0.f;
        ws[OFF_B1 + idx] = 0.f;
#pragma unroll
        for (int s = 0; s < 4; ++s) ws[OFF_AG + s * 11520 + idx] = 0.f;
    }
}

// ================= gemm1: 128 chunks(72 m) x 2 b-halves(128 b) =================
// prologue: b_ij update + softmax (duplicated x16 across blocks sharing a c-range).
__global__ __launch_bounds__(256, 1) void k_gemm1(const float* __restrict__ Xt,
                                                  const float4* __restrict__ Wr4,
                                                  const float* __restrict__ bij_old,
                                                  float* __restrict__ bij_new,
                                                  const float* __restrict__ agg_part,
                                                  float* __restrict__ s_part) {
    __shared__ float braw[720];
    __shared__ float csm[720];
    __shared__ float Ws[72 * 160];
    const int ch = blockIdx.x >> 1, bg = blockIdx.x & 1;
    const int m0 = ch * 72;
    const int c0 = (ch & 15) * 72;        // chunk sits inside one k-slice (1152/72=16)
    const int t = threadIdx.x;

    // ---- b_ij += sum_bq agg_part ; write new buffer (same value from all dups) ----
    for (int idx = t; idx < 720; idx += 256) {
        float v = bij_old[c0 * J_U + idx];
#pragma unroll
        for (int s = 0; s < 4; ++s) v += agg_part[s * 11520 + c0 * J_U + idx];
        braw[idx] = v;
        bij_new[c0 * J_U + idx] = v;
    }
    __syncthreads();
    for (int idx = t; idx < 720; idx += 256) {    // softmax over j (per-element recompute)
        const int r0 = (idx / J_U) * J_U;
        float mx = -1e30f;
#pragma unroll
        for (int j = 0; j < J_U; ++j) mx = fmaxf(mx, braw[r0 + j]);
        float sum = 0.f;
#pragma unroll
        for (int j = 0; j < J_U; ++j) sum += __expf(braw[r0 + j] - mx);
        csm[idx] = __expf(braw[idx] - mx) / sum;
    }
    __syncthreads();
    // ---- stage scaled W panel ----
    float4* Ws4 = reinterpret_cast<float4*>(Ws);
    for (int i = t; i < 2880; i += 256) {          // 72 rows x 40 float4
        const int row = i / 40, q = i - row * 40;
        const float sc = csm[row * J_U + (q >> 2)];
        const float4 w = Wr4[(size_t)(m0 + row) * 40 + q];
        Ws4[i] = make_float4(w.x * sc, w.y * sc, w.z * sc, w.w * sc);
    }
    __syncthreads();
    // ---- main loop: x from global (VMEM), w from LDS (broadcast) ----
    const int bq = t & 15, ng = t >> 4;
    const float* xb = Xt + (size_t)m0 * B_SZ + bg * 128 + bq * 8;
    float acc[8][10] = {};
    float4 xc0 = *reinterpret_cast<const float4*>(xb);
    float4 xc1 = *reinterpret_cast<const float4*>(xb + 4);
#pragma unroll 2
    for (int m = 0; m < 72; ++m) {
        const float* xn = xb + (size_t)(m + 1) * B_SZ;   // m=71 reads the pad row (unused)
        const float4 xn0 = *reinterpret_cast<const float4*>(xn);
        const float4 xn1 = *reinterpret_cast<const float4*>(xn + 4);
        const float2* wr = reinterpret_cast<const float2*>(Ws + m * N_DIM + ng * J_U);
        const float xv[8] = {xc0.x, xc0.y, xc0.z, xc0.w, xc1.x, xc1.y, xc1.z, xc1.w};
#pragma unroll
        for (int jj = 0; jj < 5; ++jj) {
            const float2 wv = wr[jj];
#pragma unroll
            for (int i = 0; i < 8; ++i) {
                acc[i][2 * jj]     += xv[i] * wv.x;
                acc[i][2 * jj + 1] += xv[i] * wv.y;
            }
        }
        xc0 = xn0; xc1 = xn1;
    }
    // ---- store split-K partials (plain stores) ----
    float* sp = s_part + (size_t)ch * 40960 + (size_t)(bg * 128 + bq * 8) * N_DIM + ng * J_U;
#pragma unroll
    for (int i = 0; i < 8; ++i) {
        float2* p = reinterpret_cast<float2*>(sp + (size_t)i * N_DIM);
#pragma unroll
        for (int jj = 0; jj < 5; ++jj) p[jj] = make_float2(acc[i][2 * jj], acc[i][2 * jj + 1]);
    }
}

// ================= squash: reduce 128 slices, squash over d -> dst =================
__global__ __launch_bounds__(320) void k_squash(const float* __restrict__ s_part,
                                                float* __restrict__ dst) {
    __shared__ float red[320];
    __shared__ float sq[160];
    const int b = blockIdx.x, t = threadIdx.x;
    const int n = t % 160, h = t / 160;
    float s = 0.f;
    const float* p = s_part + (size_t)h * 64 * 40960 + (size_t)b * N_DIM + n;
#pragma unroll 8
    for (int sl = 0; sl < 64; ++sl) s += p[(size_t)sl * 40960];
    red[t] = s;
    __syncthreads();
    if (t < 160) {
        s = red[t] + red[t + 160] + 1e-5f;   // reference adds 1e-5 BEFORE magnitudes
        sq[t] = s * s;
        red[t] = s;
    }
    __syncthreads();
    if (t < 160) {
        const int j0 = t & ~15;
        float mag = 0.f;
#pragma unroll
        for (int d = 0; d < 16; ++d) mag += sq[j0 + d];
        dst[(size_t)b * N_DIM + t] = red[t] * (sqrtf(mag) / (1.f + mag));
    }
}

// ================= gemm2: 72 c-tiles(16 c, all 8 k) x 4 b-quarters(64 b) =================
// agg_part[bq][c][j] = sum_{b in quarter} sum_{k,d} Wr[m,n]*x[b,m]*v[b,n]  (plain stores)
__global__ __launch_bounds__(256, 2) void k_gemm2(const float* __restrict__ x,
                                                  const float* __restrict__ v,
                                                  const float* __restrict__ Wr,
                                                  float* __restrict__ agg_part) {
    __shared__ float Vs[64 * 160];
    __shared__ float agg[160];
    const int c0 = (blockIdx.x >> 2) * 16, bq = blockIdx.x & 3;
    const int t = threadIdx.x;
    const int tm = t & 15, ng = t >> 4;
    const int kp = tm >> 2;               // k-pair: k = 2*kp, 2*kp+1
    const int csub = (tm & 3) * 4;        // 4 consecutive c
    // stage v quarter
    float4* Vs4 = reinterpret_cast<float4*>(Vs);
    const float4* v4 = reinterpret_cast<const float4*>(v);
    for (int i = t; i < 2560; i += 256) Vs4[i] = v4[(size_t)bq * 2560 + i];
    if (t < 160) agg[t] = 0.f;
    __syncthreads();

    float acc[8][10] = {};
    const float* xbase = x + (size_t)bq * 64 * M_DIM + c0 + csub;
    const size_t krow0 = (size_t)(2 * kp) * C_IN, krow1 = (size_t)(2 * kp + 1) * C_IN;
#pragma unroll 2
    for (int b = 0; b < 64; ++b) {
        const float* xr = xbase + (size_t)b * M_DIM;
        const float4 x0 = *reinterpret_cast<const float4*>(xr + krow0);
        const float4 x1 = *reinterpret_cast<const float4*>(xr + krow1);
        const float2* vv = reinterpret_cast<const float2*>(Vs + b * N_DIM + ng * J_U);
        const float xv[8] = {x0.x, x0.y, x0.z, x0.w, x1.x, x1.y, x1.z, x1.w};
#pragma unroll
        for (int jj = 0; jj < 5; ++jj) {
            const float2 w = vv[jj];
#pragma unroll
            for (int r = 0; r < 8; ++r) {
                acc[r][2 * jj]     += xv[r] * w.x;
                acc[r][2 * jj + 1] += xv[r] * w.y;
            }
        }
    }
    // fold with Wr (global, L3-hot), k-reduce in-thread, c/j-reduce via LDS atomics
#pragma unroll
    for (int r = 0; r < 8; ++r) {
        const int kk = r >> 2, cc = r & 3;
        const size_t m = (size_t)(2 * kp + kk) * C_IN + c0 + csub + cc;
        const float* wrow = Wr + m * N_DIM + ng * J_U;
        float psum = 0.f;
        int curj = (ng * J_U) >> 4;
#pragma unroll
        for (int jj = 0; jj < 10; ++jj) {
            const int j = (ng * J_U + jj) >> 4;
            if (j != curj) {
                atomicAdd(&agg[(csub + cc) * J_U + curj], psum);
                psum = 0.f;
                curj = j;
            }
            psum += acc[r][jj] * wrow[jj];
        }
        atomicAdd(&agg[(csub + cc) * J_U + curj], psum);
    }
    __syncthreads();
    if (t < 160) agg_part[(size_t)bq * 11520 + c0 * J_U + t] = agg[t];
}

extern "C" void kernel_launch(void* const* d_in, const int* in_sizes, int n_in,
                              void* d_out, int out_size, void* d_ws, size_t ws_size,
                              hipStream_t stream) {
    const float* x = (const float*)d_in[0];   // (256, 8, 1152) fp32
    const float* W = (const float*)d_in[1];   // (1, 1152, 10, 16, 8) fp32
    float* out = (float*)d_out;               // (256, 10, 16, 1) fp32
    float* ws  = (float*)d_ws;                // needs 38.0 MB
    float* Xt   = ws + OFF_XT;
    float* Wr   = ws + OFF_WR;
    float* sp   = ws + OFF_SP;
    float* v    = ws + OFF_V;
    float* bij0 = ws + OFF_B0;
    float* bij1 = ws + OFF_B1;
    float* agg  = ws + OFF_AG;
    const float4* Wr4 = (const float4*)Wr;

    k_prep<<<2061, 256, 0, stream>>>(x, W, ws);

    for (int it = 0; it < 4; ++it) {
        const float* bo = (it & 1) ? bij1 : bij0;
        float*       bn = (it & 1) ? bij0 : bij1;
        k_gemm1<<<256, 256, 0, stream>>>(Xt, Wr4, bo, bn, agg, sp);
        k_squash<<<256, 320, 0, stream>>>(sp, (it < 3) ? v : out);
        if (it < 3)   // last iteration's agreement is never used
            k_gemm2<<<288, 256, 0, stream>>>(x, v, Wr, agg);
    }
}